// Round 11
// baseline (30.171 us; speedup 1.0000x reference)
//
#include <hip/hip_runtime.h>
#include <hip/hip_bf16.h>

// FSMN: strided dilated depthwise conv over time + residual.
// R10 finding: register windows unobtainable (compiler reloads; VGPR 36 for a
// 38-slot ring). R8's LDS version was right but config-starved: 39KB LDS ->
// 4 blocks/CU, occ 32%.
// R11: split D into 64-col groups -> LDS tile 49 rows x 256B = 12.25KB ->
// 6+ blocks/CU, grid 12800. Stage via width-4 global_load_lds, one barrier,
// then per-thread 34-row column slice from LDS, 5 outputs x 16 static FMA.
// LDS reloads (if compiler trims W) are cheap ds_reads, not vmcnt stalls.

typedef __attribute__((address_space(1))) const unsigned int gas_u32;
typedef __attribute__((address_space(3))) unsigned int las_u32;

constexpr int B = 16;
constexpr int T = 2000;
constexpr int D = 512;
constexpr int DH = 64;             // columns per block
constexpr int NDG = D / DH;        // 8 d-groups
constexpr int NTAP = 16;           // filt rows: 0..9 left, 10 center, 11..15 right
constexpr int S = 20;              // output rows per block
constexpr int NSTRIP = T / S;      // 100
constexpr int WROWS = S + 29;      // 49 staged rows [t0-20 .. t0+28]
constexpr int NXCD = 8;

__global__ __launch_bounds__(256, 6) void fsmn_lds_kernel(
    const float* __restrict__ x,      // (B,T,D)
    const float* __restrict__ filt,   // (16,D)
    float* __restrict__ out)          // (B,T,D)
{
    __shared__ float smem[WROWS * DH];   // 12544 B

    // grid = B*NDG*NSTRIP = 12800; decode from the REMAPPED id so each XCD's
    // chunk is a contiguous strip range (halo neighbors share that XCD's L2).
    const int nbl = B * NDG * NSTRIP;        // 12800
    const int cpx = nbl / NXCD;              // 1600
    int bid = blockIdx.x;
    bid = (bid & (NXCD - 1)) * cpx + (bid >> 3);   // chunked XCD swizzle

    const int strip = bid % NSTRIP;
    const int rest  = bid / NSTRIP;          // 0..127
    const int dgrp  = rest & (NDG - 1);
    const int b     = rest >> 3;
    const int t0    = strip * S;
    const int d0    = dgrp * DH;

    const int tid  = (int)threadIdx.x;
    const int wave = tid >> 6;
    const int lane = tid & 63;

    // ---- stage 49 rows x 256B into LDS; wave w does rows m = w, w+4, ... ----
    const float* gx = x + (size_t)(b * T) * D + d0;
#pragma unroll
    for (int j = 0; j < 13; ++j) {
        const int m = wave + 4 * j;
        if (m < WROWS) {                          // wave-uniform
            const int p = t0 - 20 + m;
            if (p >= 0 && p < T) {                // block-uniform scalar guard
                const float* src = gx + (size_t)p * D + lane;   // 4B/lane
                __builtin_amdgcn_global_load_lds(
                    (gas_u32*)src,
                    (las_u32*)&smem[m * DH],      // wave-uniform base; HW adds lane*4
                    4, 0, 0);
            } else {
                smem[m * DH + lane] = 0.0f;       // zero out-of-range row
            }
        }
    }

    // filter taps for this column (global loads overlap the staging drain);
    // residual folded into center tap.
    const int c   = tid & (DH - 1);               // column 0..63
    const int grp = tid >> 6;                     // t-subgroup 0..3 (== wave)
    float F[NTAP];
#pragma unroll
    for (int k = 0; k < NTAP; ++k) F[k] = filt[k * D + d0 + c];
    F[10] += 1.0f;

    __syncthreads();   // drains vmcnt (global_load_lds) + lgkmcnt

    // ---- per-thread column slice: outputs i0..i0+4 need rows i0..i0+33 ----
    const int i0 = grp * 5;
    float W[34];
#pragma unroll
    for (int r = 0; r < 34; ++r) W[r] = smem[(i0 + r) * DH + c];

    float* op = out + (size_t)(b * T + t0 + i0) * D + d0 + c;
#pragma unroll
    for (int j = 0; j < 5; ++j) {
        // output i = i0+j uses rows (i0+) j+2k (left), j+20 (center),
        // j+21+2k (right) — all static indices after unroll.
        float a = W[j + 20] * F[10];
#pragma unroll
        for (int k = 0; k < 10; ++k) a = fmaf(W[j + 2 * k], F[k], a);
#pragma unroll
        for (int k = 0; k < 5; ++k)  a = fmaf(W[j + 21 + 2 * k], F[11 + k], a);
        // nontemporal: output never re-read — keep L2/L3 for the input halo
        __builtin_nontemporal_store(a, &op[(size_t)j * D]);
    }
}

extern "C" void kernel_launch(void* const* d_in, const int* in_sizes, int n_in,
                              void* d_out, int out_size, void* d_ws, size_t ws_size,
                              hipStream_t stream) {
    const float* x    = (const float*)d_in[0];
    const float* filt = (const float*)d_in[1];
    float* out        = (float*)d_out;

    const int grid = B * NDG * NSTRIP;   // 12800 blocks, /8 XCDs evenly
    fsmn_lds_kernel<<<grid, 256, 0, stream>>>(x, filt, out);
}